// Round 10
// baseline (291.695 us; speedup 1.0000x reference)
//
#include <hip/hip_runtime.h>
#include <hip/hip_bf16.h>

// ---------------------------------------------------------------------------
// GCNEncoder: 3x (GCNConv -> [BN -> LeakyReLU]), N=50000 nodes, E=800000 edges.
//   Layer1 aggregate-first:  out1 = (A_hat X) W1 + b1
//   Layers2/3 transform-first: hd = (act(prev) @ W) * dinv; out = gather + bias
// R24 = R23 (bf16 pre-scaled messages) + two agg-chain cuts:
//   1. srcs64[n][64]: first 64 src ids per node at FIXED stride -> agg loads
//      them rs-independently, in parallel with row_start/dinv/self-row.
//      Kills the elist dependency round (serial chain 3 VMEM rounds -> 2).
//      Masked slots select s=v BEFORE the gather (pad never dereferenced).
//      deg>64 overflow uses the CSR elist path as before.
//   2. uint4 lanes: j=L&7 covers 16B of the 128B row, r=L>>3 -> 8 edges per
//      gather instr (halved instr count); 32-edge break granularity with 4
//      instrs in flight => deg<=32 (89% of nodes) gathers in ONE round.
// Kept: radix CSR, merged setup+cnt, separate stat_k, f32-LDS gemm.
// ---------------------------------------------------------------------------

#define LEAKY 0.01f
#define EPS_BN 1e-5f
#define NBIN 256
#define CB   128

typedef unsigned int uint32;

static __device__ __forceinline__ float bf_lo(uint32 u) { return __uint_as_float(u << 16); }
static __device__ __forceinline__ float bf_hi(uint32 u) { return __uint_as_float(u & 0xFFFF0000u); }

static __device__ __forceinline__ uint32 pack_bf(float x, float y) {
    __hip_bfloat16 bx = __float2bfloat16(x), by = __float2bfloat16(y);
    return (uint32)(*(unsigned short*)&bx) | ((uint32)(*(unsigned short*)&by) << 16);
}

// ---- merged: dtype detect + param convert (b<83) | zero stats (b==83) |
// ----         radix bin count (84..211)  -- all independent work ----------

__global__ __launch_bounds__(256) void setup_cnt_k(
    const uint32* __restrict__ x, int* __restrict__ flag,
    const void* p0, const void* p1, const void* p2, const void* p3,
    const void* p4, const void* p5, const void* p6, const void* p7,
    const void* p8, const void* p9, float* __restrict__ dst,
    float* __restrict__ stats1, float* __restrict__ stats2,
    const int* __restrict__ dstE, int* __restrict__ pbc, int E) {
    const int b = blockIdx.x, t = threadIdx.x;
    if (b < 83) {
        __shared__ int sd[256];
        int c = 0;
        for (int j = 0; j < 16; ++j) {
            uint32 w = x[t * 16 + j];
            uint32 m = w & 0x7FFFu;
            uint32 e = (w >> 7) & 0xFFu;
            if (m == 0u || (e >= 100u && e <= 150u)) ++c;
        }
        sd[t] = c;
        __syncthreads();
        for (int off = 128; off > 0; off >>= 1) {
            if (t < off) sd[t] += sd[t + off];
            __syncthreads();
        }
        bool bf = (sd[0] >= 3072);
        if (b == 0 && t == 0) *flag = bf ? 1 : 0;
        int i = b * 256 + t;
        if (i < 21120) {
            const void* p;
            int j;
            if      (i <  8192) { p = p0; j = i;         }
            else if (i <  8320) { p = p1; j = i - 8192;  }
            else if (i <  8448) { p = p2; j = i - 8320;  }
            else if (i <  8576) { p = p3; j = i - 8448;  }
            else if (i < 16768) { p = p4; j = i - 8576;  }
            else if (i < 16832) { p = p5; j = i - 16768; }
            else if (i < 16896) { p = p6; j = i - 16832; }
            else if (i < 16960) { p = p7; j = i - 16896; }
            else if (i < 21056) { p = p8; j = i - 16960; }
            else                { p = p9; j = i - 21056; }
            dst[i] = bf ? __bfloat162float(((const __hip_bfloat16*)p)[j])
                        : ((const float*)p)[j];
        }
    } else if (b == 83) {
        stats1[t] = 0.f;
        if (t < 128) stats2[t] = 0.f;
    } else {
        __shared__ int c[NBIN];
        c[t] = 0;
        __syncthreads();
        const int cb = b - 84;
        const int chunk = (E + CB - 1) / CB;
        const int lo = cb * chunk, hi = min(E, lo + chunk);
        for (int i = lo + t; i < hi; i += 256)
            atomicAdd(&c[dstE[i] >> 8], 1);
        __syncthreads();
        pbc[t * CB + cb] = c[t];
    }
}

// one block, 256 threads (thread j owns bin j); prefix over CB in registers.
__global__ __launch_bounds__(256) void scan2_k(int* __restrict__ pbc,
                                               int* __restrict__ bb,
                                               int* __restrict__ row_end, int E) {
    const int j = threadIdx.x;
    int4 vals[CB / 4];
    int tot = 0;
#pragma unroll
    for (int c = 0; c < CB / 4; ++c) {
        vals[c] = ((const int4*)(pbc + j * CB))[c];
        tot += vals[c].x + vals[c].y + vals[c].z + vals[c].w;
    }
    __shared__ int sd[NBIN];
    sd[j] = tot;
    __syncthreads();
    for (int off = 1; off < NBIN; off <<= 1) {
        int x = (j >= off) ? sd[j - off] : 0;
        __syncthreads();
        sd[j] += x;
        __syncthreads();
    }
    int run = sd[j] - tot;   // exclusive bucket base
    bb[j] = run;
    if (j == 0) *row_end = E;
#pragma unroll
    for (int c = 0; c < CB / 4; ++c) {
        int4 v = vals[c];
        int a0 = run; run += v.x;
        int a1 = run; run += v.y;
        int a2 = run; run += v.z;
        int a3 = run; run += v.w;
        ((int4*)(pbc + j * CB))[c] = make_int4(a0, a1, a2, a3);
    }
}

// packed edge record: (src << 8) | (dst & 255). bin implied by position.
__global__ __launch_bounds__(256) void scat_k(const int* __restrict__ src,
                                              const int* __restrict__ dst,
                                              const int* __restrict__ pbc,
                                              uint32* __restrict__ ebuf, int E) {
    __shared__ int cur[NBIN];
    cur[threadIdx.x] = pbc[threadIdx.x * CB + blockIdx.x];
    __syncthreads();
    const int chunk = (E + CB - 1) / CB;
    const int lo = blockIdx.x * chunk, hi = min(E, lo + chunk);
    for (int i = lo + threadIdx.x; i < hi; i += 256) {
        int d = dst[i];
        int p = atomicAdd(&cur[d >> 8], 1);      // LDS atomic
        ebuf[p] = ((uint32)src[i] << 8) | (uint32)(d & 255);
    }
}

// one block per bin (256 nodes): CSR rows + elist + srcs64 (first-64 fixed
// stride) + xs[v] = x[v]*dinv[v] bf16 + dinv.
__global__ __launch_bounds__(256) void fill2_k(
    const uint32* __restrict__ ebuf, const int* __restrict__ bb,
    int* __restrict__ row_start, int* __restrict__ elist,
    int* __restrict__ srcs64,
    const void* __restrict__ xv, const int* __restrict__ flag,
    uint2* __restrict__ xs, float* __restrict__ dinv, int n) {
    __shared__ int cntl[NBIN], curl[NBIN], sd[NBIN], basep[NBIN];
    const int j = blockIdx.x, t = threadIdx.x;
    const int lo = j << 8;
    const int hi = min(n, lo + 256);
    const int nn = hi - lo;
    if (nn <= 0) return;
    const int eb = bb[j], ee = bb[j + 1];

    cntl[t] = 0;
    __syncthreads();
    for (int i = eb + t; i < ee; i += 256)
        atomicAdd(&cntl[ebuf[i] & 255u], 1);     // LDS atomic
    __syncthreads();
    int cv = cntl[t];
    sd[t] = cv;
    __syncthreads();
    for (int off = 1; off < NBIN; off <<= 1) {
        int x = (t >= off) ? sd[t - off] : 0;
        __syncthreads();
        sd[t] += x;
        __syncthreads();
    }
    int pref = sd[t] - cv;                        // exclusive
    if (t < nn) row_start[lo + t] = eb + pref;
    curl[t] = pref;
    basep[t] = pref;
    __syncthreads();
    for (int i = eb + t; i < ee; i += 256) {
        uint32 e = ebuf[i];
        int dl = (int)(e & 255u);
        int src = (int)(e >> 8);
        int p = atomicAdd(&curl[dl], 1);          // LDS atomic
        elist[eb + p] = src;
        int slot = p - basep[dl];
        if (slot < 64) srcs64[(size_t)(lo + dl) * 64 + slot] = src;
    }
    // per-thread node row: xs = x * dinv, bf16
    const int v = lo + t;
    if (v < hi) {
        const bool bf = (*flag != 0);
        float d = rsqrtf((float)(cntl[t] + 1));
        dinv[v] = d;
        if (bf) {
#pragma unroll
            for (int c = 0; c < 16; ++c) {
                uint2 u = ((const uint2*)xv)[(size_t)v * 16 + c];
                float f0 = bf_lo(u.x) * d, f1 = bf_hi(u.x) * d;
                float f2 = bf_lo(u.y) * d, f3 = bf_hi(u.y) * d;
                xs[(size_t)v * 16 + c] = make_uint2(pack_bf(f0, f1), pack_bf(f2, f3));
            }
        } else {
#pragma unroll
            for (int c = 0; c < 16; ++c) {
                float4 f = ((const float4*)xv)[(size_t)v * 16 + c];
                xs[(size_t)v * 16 + c] =
                    make_uint2(pack_bf(f.x * d, f.y * d), pack_bf(f.z * d, f.w * d));
            }
        }
    }
}

// ---------------- aggregation: bf16 pre-scaled rows, one wave/node ---------
// B: [n][8] uint4 rows (64ch bf16, already *dinv[src]). Lane j=L&7 covers
// 16B (8ch), r=L>>3 edge slot -> 8 edges per gather instr. First 64 edges
// come from srcs64 (fixed stride, loaded in round 1 parallel with row_start/
// dinv/self-row -> no elist dependency round). 32-edge break granularity,
// 4 gathers in flight: deg<=32 gathers in ONE latency round. Masked slots
// select s=v BEFORE the gather. deg>64 falls back to elist. 3-step butterfly
// (xor 8,16,32); epilogue on 8 lanes, one uint4 (bf16) / two float4 (f32).

template <bool BIAS, bool OUT_NATIVE>
__global__ __launch_bounds__(256) void agg_k(
    const uint4* __restrict__ B, const float* __restrict__ dinv,
    const int* __restrict__ row_start, const int* __restrict__ elist,
    const int* __restrict__ srcs64, const float* __restrict__ bias,
    void* __restrict__ outv, const int* __restrict__ flag, int n) {
    const int v = blockIdx.x * 4 + (threadIdx.x >> 6);
    if (v >= n) return;
    const int L = threadIdx.x & 63;
    const int r = L >> 3;      // edge slot 0..7
    const int j = L & 7;       // uint4 (8ch) chunk within 128B row

    // round 1: all independent loads
    const int sid = srcs64[(size_t)v * 64 + L];
    const int rs = row_start[v], re = row_start[v + 1];
    const float dv = dinv[v];
    const uint4 su = B[(size_t)v * 8 + j];
    const int deg = re - rs;

    float acc[8];
#pragma unroll
    for (int i = 0; i < 8; ++i) acc[i] = 0.f;
    if (r == 0) {              // self-loop (row already has dinv folded)
        acc[0] = bf_lo(su.x); acc[1] = bf_hi(su.x);
        acc[2] = bf_lo(su.y); acc[3] = bf_hi(su.y);
        acc[4] = bf_lo(su.z); acc[5] = bf_hi(su.z);
        acc[6] = bf_lo(su.w); acc[7] = bf_hi(su.w);
    }

    // first 64 edges via srcs64 (round 2: gathers only)
#pragma unroll 1
    for (int k = 0; k < 2; ++k) {                // 32-edge halves
        if (k * 32 >= deg) break;
#pragma unroll
        for (int t = 0; t < 4; ++t) {            // 4 gathers in flight
            int e = k * 32 + t * 8 + r;
            int s = __shfl(sid, e);
            bool in = (e < deg);
            s = in ? s : v;                      // pad never dereferenced
            float m = in ? 1.f : 0.f;
            uint4 u = B[(size_t)s * 8 + j];
            acc[0] = fmaf(m, bf_lo(u.x), acc[0]);
            acc[1] = fmaf(m, bf_hi(u.x), acc[1]);
            acc[2] = fmaf(m, bf_lo(u.y), acc[2]);
            acc[3] = fmaf(m, bf_hi(u.y), acc[3]);
            acc[4] = fmaf(m, bf_lo(u.z), acc[4]);
            acc[5] = fmaf(m, bf_hi(u.z), acc[5]);
            acc[6] = fmaf(m, bf_lo(u.w), acc[6]);
            acc[7] = fmaf(m, bf_hi(u.w), acc[7]);
        }
    }

    // overflow: edges 64.. via elist (rare for Poisson-16 degrees)
    for (int base = rs + 64; base < re; base += 64) {
        int ed = elist[min(base + L, re - 1)];
#pragma unroll 1
        for (int k = 0; k < 2; ++k) {
            if (base + k * 32 >= re) break;
#pragma unroll
            for (int t = 0; t < 4; ++t) {
                int e = k * 32 + t * 8 + r;
                int s = __shfl(ed, e);
                float m = (base + e < re) ? 1.f : 0.f;
                uint4 u = B[(size_t)s * 8 + j];
                acc[0] = fmaf(m, bf_lo(u.x), acc[0]);
                acc[1] = fmaf(m, bf_hi(u.x), acc[1]);
                acc[2] = fmaf(m, bf_lo(u.y), acc[2]);
                acc[3] = fmaf(m, bf_hi(u.y), acc[3]);
                acc[4] = fmaf(m, bf_lo(u.z), acc[4]);
                acc[5] = fmaf(m, bf_hi(u.z), acc[5]);
                acc[6] = fmaf(m, bf_lo(u.w), acc[6]);
                acc[7] = fmaf(m, bf_hi(u.w), acc[7]);
            }
        }
    }

    // reduce 8 edge slots (lane bits 3..5)
#pragma unroll
    for (int i = 0; i < 8; ++i) {
        acc[i] += __shfl_xor(acc[i], 8);
        acc[i] += __shfl_xor(acc[i], 16);
        acc[i] += __shfl_xor(acc[i], 32);
    }

    if (r == 0) {              // lanes 0..7, one 16B chunk each
        float b[8] = {0.f, 0.f, 0.f, 0.f, 0.f, 0.f, 0.f, 0.f};
        if constexpr (BIAS) {
            float4 b0 = ((const float4*)bias)[j * 2 + 0];
            float4 b1 = ((const float4*)bias)[j * 2 + 1];
            b[0] = b0.x; b[1] = b0.y; b[2] = b0.z; b[3] = b0.w;
            b[4] = b1.x; b[5] = b1.y; b[6] = b1.z; b[7] = b1.w;
        }
        float o[8];
#pragma unroll
        for (int i = 0; i < 8; ++i) o[i] = fmaf(dv, acc[i], b[i]);
        bool f32out = false;
        if constexpr (OUT_NATIVE) f32out = (*flag == 0);
        if (f32out) {
            ((float4*)outv)[(size_t)v * 16 + j * 2 + 0] =
                make_float4(o[0], o[1], o[2], o[3]);
            ((float4*)outv)[(size_t)v * 16 + j * 2 + 1] =
                make_float4(o[4], o[5], o[6], o[7]);
        } else {
            ((uint4*)outv)[(size_t)v * 8 + j] =
                make_uint4(pack_bf(o[0], o[1]), pack_bf(o[2], o[3]),
                           pack_bf(o[4], o[5]), pack_bf(o[6], o[7]));
        }
    }
}

// ---------------- BN stats over bf16 [n,C] buffer ----------------
// uint2 per lane (4 channels); 256 blocks (small atomic fan-in).

template <int C2>
__global__ __launch_bounds__(256) void stat_k(const uint2* __restrict__ buf,
                                              float* __restrict__ stats, int n) {
    constexpr int LPR = C2 / 2;      // lanes per row
    constexpr int RPB = 256 / LPR;   // rows per block-iteration
    constexpr int C = 2 * C2;
    const int lp = threadIdx.x % LPR;
    const int rg = threadIdx.x / LPR;
    float s0 = 0.f, s1 = 0.f, s2 = 0.f, s3 = 0.f;
    float q0 = 0.f, q1 = 0.f, q2 = 0.f, q3 = 0.f;
    for (int r = blockIdx.x * RPB + rg; r < n; r += gridDim.x * RPB) {
        uint2 u = buf[(size_t)r * LPR + lp];
        float f0 = bf_lo(u.x), f1 = bf_hi(u.x);
        float f2 = bf_lo(u.y), f3 = bf_hi(u.y);
        s0 += f0; q0 = fmaf(f0, f0, q0);
        s1 += f1; q1 = fmaf(f1, f1, q1);
        s2 += f2; q2 = fmaf(f2, f2, q2);
        s3 += f3; q3 = fmaf(f3, f3, q3);
    }
    __shared__ float sd[2 * C];
    for (int i = threadIdx.x; i < 2 * C; i += 256) sd[i] = 0.f;
    __syncthreads();
    atomicAdd(&sd[4 * lp + 0], s0);
    atomicAdd(&sd[4 * lp + 1], s1);
    atomicAdd(&sd[4 * lp + 2], s2);
    atomicAdd(&sd[4 * lp + 3], s3);
    atomicAdd(&sd[C + 4 * lp + 0], q0);
    atomicAdd(&sd[C + 4 * lp + 1], q1);
    atomicAdd(&sd[C + 4 * lp + 2], q2);
    atomicAdd(&sd[C + 4 * lp + 3], q3);
    __syncthreads();
    for (int i = threadIdx.x; i < 2 * C; i += 256) atomicAdd(&stats[i], sd[i]);
}

// ---------------- GEMM: out = epilogue( act(A) @ W ) ----------------
// A [n,K] bf16 flat, W [K,N] f32. XOR-swizzled Ast staging.
// AFFS: in-block BN coefs from raw stats. BIAS: +bias[col]. DINV: row scale
// (pre-folds dinv into the bf16 output rows for the next aggregation).

template <int K, int N, int MR, bool AFFS, bool BIAS, bool DINV>
__global__ __launch_bounds__(256) void gemm_k(
    const __hip_bfloat16* __restrict__ A, const float* __restrict__ W,
    const float* __restrict__ stats, const float* __restrict__ g,
    const float* __restrict__ be, float invN,
    const float* __restrict__ bias, const float* __restrict__ dinv,
    __hip_bfloat16* __restrict__ out, int n) {
    constexpr int CG = N / 4;        // threads across columns
    constexpr int RG = 256 / CG;     // row groups
    constexpr int TM = RG * MR;      // rows per block
    __shared__ __align__(16) float Ws[K * N];
    __shared__ __align__(16) float Ast[K * TM];
    __shared__ float cf[AFFS ? 2 * K : 1];

    const int tid = threadIdx.x;
    if constexpr (AFFS) {
        if (tid < K) {
            float mean = stats[tid] * invN;
            float var  = fmaxf(fmaf(-mean, mean, stats[K + tid] * invN), 0.f);
            float a    = g[tid] * rsqrtf(var + EPS_BN);
            cf[tid]     = a;
            cf[K + tid] = be[tid] - mean * a;
        }
        __syncthreads();
    }

    for (int i = tid; i < K * N / 4; i += 256)
        ((float4*)Ws)[i] = ((const float4*)W)[i];

    const int row0 = blockIdx.x * TM;
    constexpr int KC = K / 4;
    for (int i = tid; i < TM * KC; i += 256) {
        int r  = i / KC;
        int c4 = (i - r * KC) * 4;
        int gr = row0 + r;
        float f0 = 0.f, f1 = 0.f, f2 = 0.f, f3 = 0.f;
        if (gr < n) {
            uint2 u = *(const uint2*)(A + (size_t)gr * K + c4);
            f0 = bf_lo(u.x); f1 = bf_hi(u.x);
            f2 = bf_lo(u.y); f3 = bf_hi(u.y);
            if constexpr (AFFS) {
                f0 = fmaf(cf[c4 + 0], f0, cf[K + c4 + 0]); f0 = f0 > 0.f ? f0 : LEAKY * f0;
                f1 = fmaf(cf[c4 + 1], f1, cf[K + c4 + 1]); f1 = f1 > 0.f ? f1 : LEAKY * f1;
                f2 = fmaf(cf[c4 + 2], f2, cf[K + c4 + 2]); f2 = f2 > 0.f ? f2 : LEAKY * f2;
                f3 = fmaf(cf[c4 + 3], f3, cf[K + c4 + 3]); f3 = f3 > 0.f ? f3 : LEAKY * f3;
            }
        }
        const int rr = r ^ (4 * ((c4 >> 2) & 7));
        Ast[(c4 + 0) * TM + rr] = f0;
        Ast[(c4 + 1) * TM + rr] = f1;
        Ast[(c4 + 2) * TM + rr] = f2;
        Ast[(c4 + 3) * TM + rr] = f3;
    }
    __syncthreads();

    const int tr = tid / CG, tc = tid % CG;
    float acc[MR][4];
#pragma unroll
    for (int m = 0; m < MR; ++m)
#pragma unroll
        for (int j = 0; j < 4; ++j) acc[m][j] = 0.f;

#pragma unroll 4
    for (int k = 0; k < K; ++k) {
        float4 w = *(const float4*)&Ws[k * N + tc * 4];
        const int sk = 4 * ((k >> 2) & 7);
        float am[MR];
        if constexpr (MR == 4) {
            float4 t = *(const float4*)&Ast[k * TM + ((tr * 4) ^ sk)];
            am[0] = t.x; am[1] = t.y; am[2] = t.z; am[3] = t.w;
        } else {
            float2 t = *(const float2*)&Ast[k * TM + ((tr * 2) ^ sk)];
            am[0] = t.x; am[1] = t.y;
        }
#pragma unroll
        for (int m = 0; m < MR; ++m) {
            acc[m][0] = fmaf(am[m], w.x, acc[m][0]);
            acc[m][1] = fmaf(am[m], w.y, acc[m][1]);
            acc[m][2] = fmaf(am[m], w.z, acc[m][2]);
            acc[m][3] = fmaf(am[m], w.w, acc[m][3]);
        }
    }

    float bv[4] = {0.f, 0.f, 0.f, 0.f};
    if constexpr (BIAS) {
#pragma unroll
        for (int j = 0; j < 4; ++j) bv[j] = bias[tc * 4 + j];
    }

#pragma unroll
    for (int m = 0; m < MR; ++m) {
        int gr = row0 + tr * MR + m;
        float sc = 1.f;
        if constexpr (DINV) sc = (gr < n) ? dinv[gr] : 0.f;
        float val[4];
#pragma unroll
        for (int j = 0; j < 4; ++j) {
            float v = acc[m][j];
            if constexpr (BIAS) v += bv[j];
            else                v *= sc;
            val[j] = v;
        }
        if (gr < n) {
            __attribute__((aligned(8))) __hip_bfloat16 pk[4];
#pragma unroll
            for (int j = 0; j < 4; ++j) pk[j] = __float2bfloat16(val[j]);
            *(uint2*)(out + (size_t)gr * N + tc * 4) = *(const uint2*)pk;
        }
    }
}

// ---------------- host ----------------

extern "C" void kernel_launch(void* const* d_in, const int* in_sizes, int n_in,
                              void* d_out, int out_size, void* d_ws, size_t ws_size,
                              hipStream_t stream) {
    const int n = in_sizes[0] / 64;   // 50000
    const int E = in_sizes[1] / 2;    // 800000

    const void* x  = d_in[0];
    const int*  ei = (const int*)d_in[1];

    // workspace carve (256B aligned) — total ~45 MB
    char* w = (char*)d_ws;
    auto alloc = [&](size_t bytes) -> void* {
        void* p = (void*)w;
        w += (bytes + 255) & ~(size_t)255;
        return p;
    };
    int*   flag      = (int*)alloc(256);
    float* Wf        = (float*)alloc(21120 * 4);            // converted params
    int*   pbc       = (int*)alloc((size_t)CB * NBIN * 4);
    int*   bb        = (int*)alloc((NBIN + 2) * 4);
    int*   row_start = (int*)alloc((size_t)(n + 1) * 4);
    int*   elist     = (int*)alloc((size_t)E * 4);
    int*   srcs64    = (int*)alloc((size_t)n * 64 * 4);     // first-64 src ids
    uint32* ebuf     = (uint32*)alloc((size_t)E * 4);       // packed (src<<8)|dl
    float* dinv      = (float*)alloc((size_t)n * 4);
    float* stats1    = (float*)alloc(256 * 4);
    float* stats2    = (float*)alloc(128 * 4);
    uint2* xs        = (uint2*)alloc((size_t)n * 16 * 8);   // x*dinv bf16 rows
    __hip_bfloat16* B1 = (__hip_bfloat16*)alloc((size_t)n * 64 * 2);   // AX / hd
    __hip_bfloat16* B2 = (__hip_bfloat16*)alloc((size_t)n * 128 * 2);  // out1/out2

    // param offsets inside Wf
    float* W1f = Wf + 0;     float* b1f = Wf + 8192;
    float* g1f = Wf + 8320;  float* be1f = Wf + 8448;
    float* W2f = Wf + 8576;  float* b2f = Wf + 16768;
    float* g2f = Wf + 16832; float* be2f = Wf + 16896;
    float* W3f = Wf + 16960; float* b3f = Wf + 21056;

    const float invN = 1.0f / (float)n;
    const int nbins = (n + 255) >> 8;        // bins of 256 nodes
    const int ab    = (n + 3) / 4;           // one wave per node, 4 waves/block

    // 1: detect + cvt params + zero stats + bin count (merged, independent)
    setup_cnt_k<<<212, 256, 0, stream>>>((const uint32*)x, flag,
        d_in[2], d_in[3], d_in[4], d_in[5], d_in[6], d_in[7], d_in[8], d_in[9],
        d_in[10], d_in[11], Wf, stats1, stats2, ei + E, pbc, E);
    // 2-4: atomic-free radix CSR build + srcs64 + pre-scaled bf16 xs
    scan2_k<<<1, 256, 0, stream>>>(pbc, bb, row_start + n, E);
    scat_k<<<CB, 256, 0, stream>>>(ei, ei + E, pbc, ebuf, E);
    fill2_k<<<nbins, 256, 0, stream>>>(ebuf, bb, row_start, elist, srcs64,
                                       x, flag, xs, dinv, n);

    // Layer 1 (aggregate-first): B1 = A_hat x ; out1(B2) = B1@W1 + b1 ; stats1
    agg_k<false, false><<<ab, 256, 0, stream>>>((const uint4*)xs, dinv, row_start,
                                                elist, srcs64, nullptr, B1, flag, n);
    gemm_k<64, 128, 4, false, true, false><<<(n + 31) / 32, 256, 0, stream>>>(
        B1, W1f, nullptr, nullptr, nullptr, 0.f, b1f, nullptr, B2, n);
    stat_k<64><<<256, 256, 0, stream>>>((const uint2*)B2, stats1, n);

    // Layer 2: hd(B1) = (BN+leaky(out1)@W2)*dinv ; out2(B2) = gather + b2 ; stats2
    gemm_k<128, 64, 4, true, false, true><<<(n + 63) / 64, 256, 0, stream>>>(
        B2, W2f, stats1, g1f, be1f, invN, nullptr, dinv, B1, n);
    agg_k<true, false><<<ab, 256, 0, stream>>>((const uint4*)B1, dinv, row_start,
                                               elist, srcs64, b2f, B2, flag, n);
    stat_k<32><<<256, 256, 0, stream>>>((const uint2*)B2, stats2, n);

    // Layer 3: hd(B1) = (BN+leaky(out2)@W3)*dinv ; out = gather + b3 (native)
    gemm_k<64, 64, 4, true, false, true><<<(n + 63) / 64, 256, 0, stream>>>(
        B2, W3f, stats2, g2f, be2f, invN, nullptr, dinv, B1, n);
    agg_k<true, true><<<ab, 256, 0, stream>>>((const uint4*)B1, dinv, row_start,
                                              elist, srcs64, b3f, d_out, flag, n);
}

// Round 11
// 286.845 us; speedup vs baseline: 1.0169x; 1.0169x over previous
//
#include <hip/hip_runtime.h>
#include <hip/hip_bf16.h>

// ---------------------------------------------------------------------------
// GCNEncoder: 3x (GCNConv -> [BN -> LeakyReLU]), N=50000 nodes, E=800000 edges.
//   Layer1 aggregate-first:  out1 = (A_hat X) W1 + b1
//   Layers2/3 transform-first: hd = (act(prev) @ W) * dinv; out = gather + bias
// R25 = R23 (best measured: 284.45us, absmax 0.0078). Session-final config.
// Messages are bf16 rows PRE-SCALED by dinv[src]:
//   - xs[v] = x[v]*dinv[v] (bf16, fill2); hd = (act@W)*dinv (gemm DINV path).
//   - agg gathers 128B bf16 rows; NO per-edge scale gather, shfl halved.
// Agg bracket (R15/R20/R21/R22/R24): wave-per-node pull with 16-edge batches,
// 4 gathers in flight, early break is the local optimum; agg sits at a
// scattered L2/L3 line-touch latency floor (~1.6M touches/pass, cross-XCD
// replication: FETCH ~18MB/pass >> 6.4MB working set).
// Kept: radix CSR, merged setup+cnt, separate stat_k, f32-LDS gemm.
// ---------------------------------------------------------------------------

#define LEAKY 0.01f
#define EPS_BN 1e-5f
#define NBIN 256
#define CB   128

typedef unsigned int uint32;

static __device__ __forceinline__ float bf_lo(uint32 u) { return __uint_as_float(u << 16); }
static __device__ __forceinline__ float bf_hi(uint32 u) { return __uint_as_float(u & 0xFFFF0000u); }

static __device__ __forceinline__ uint32 pack_bf(float x, float y) {
    __hip_bfloat16 bx = __float2bfloat16(x), by = __float2bfloat16(y);
    return (uint32)(*(unsigned short*)&bx) | ((uint32)(*(unsigned short*)&by) << 16);
}

// ---- merged: dtype detect + param convert (b<83) | zero stats (b==83) |
// ----         radix bin count (84..211)  -- all independent work ----------

__global__ __launch_bounds__(256) void setup_cnt_k(
    const uint32* __restrict__ x, int* __restrict__ flag,
    const void* p0, const void* p1, const void* p2, const void* p3,
    const void* p4, const void* p5, const void* p6, const void* p7,
    const void* p8, const void* p9, float* __restrict__ dst,
    float* __restrict__ stats1, float* __restrict__ stats2,
    const int* __restrict__ dstE, int* __restrict__ pbc, int E) {
    const int b = blockIdx.x, t = threadIdx.x;
    if (b < 83) {
        __shared__ int sd[256];
        int c = 0;
        for (int j = 0; j < 16; ++j) {
            uint32 w = x[t * 16 + j];
            uint32 m = w & 0x7FFFu;
            uint32 e = (w >> 7) & 0xFFu;
            if (m == 0u || (e >= 100u && e <= 150u)) ++c;
        }
        sd[t] = c;
        __syncthreads();
        for (int off = 128; off > 0; off >>= 1) {
            if (t < off) sd[t] += sd[t + off];
            __syncthreads();
        }
        bool bf = (sd[0] >= 3072);
        if (b == 0 && t == 0) *flag = bf ? 1 : 0;
        int i = b * 256 + t;
        if (i < 21120) {
            const void* p;
            int j;
            if      (i <  8192) { p = p0; j = i;         }
            else if (i <  8320) { p = p1; j = i - 8192;  }
            else if (i <  8448) { p = p2; j = i - 8320;  }
            else if (i <  8576) { p = p3; j = i - 8448;  }
            else if (i < 16768) { p = p4; j = i - 8576;  }
            else if (i < 16832) { p = p5; j = i - 16768; }
            else if (i < 16896) { p = p6; j = i - 16832; }
            else if (i < 16960) { p = p7; j = i - 16896; }
            else if (i < 21056) { p = p8; j = i - 16960; }
            else                { p = p9; j = i - 21056; }
            dst[i] = bf ? __bfloat162float(((const __hip_bfloat16*)p)[j])
                        : ((const float*)p)[j];
        }
    } else if (b == 83) {
        stats1[t] = 0.f;
        if (t < 128) stats2[t] = 0.f;
    } else {
        __shared__ int c[NBIN];
        c[t] = 0;
        __syncthreads();
        const int cb = b - 84;
        const int chunk = (E + CB - 1) / CB;
        const int lo = cb * chunk, hi = min(E, lo + chunk);
        for (int i = lo + t; i < hi; i += 256)
            atomicAdd(&c[dstE[i] >> 8], 1);
        __syncthreads();
        pbc[t * CB + cb] = c[t];
    }
}

// one block, 256 threads (thread j owns bin j); prefix over CB in registers.
__global__ __launch_bounds__(256) void scan2_k(int* __restrict__ pbc,
                                               int* __restrict__ bb,
                                               int* __restrict__ row_end, int E) {
    const int j = threadIdx.x;
    int4 vals[CB / 4];
    int tot = 0;
#pragma unroll
    for (int c = 0; c < CB / 4; ++c) {
        vals[c] = ((const int4*)(pbc + j * CB))[c];
        tot += vals[c].x + vals[c].y + vals[c].z + vals[c].w;
    }
    __shared__ int sd[NBIN];
    sd[j] = tot;
    __syncthreads();
    for (int off = 1; off < NBIN; off <<= 1) {
        int x = (j >= off) ? sd[j - off] : 0;
        __syncthreads();
        sd[j] += x;
        __syncthreads();
    }
    int run = sd[j] - tot;   // exclusive bucket base
    bb[j] = run;
    if (j == 0) *row_end = E;
#pragma unroll
    for (int c = 0; c < CB / 4; ++c) {
        int4 v = vals[c];
        int a0 = run; run += v.x;
        int a1 = run; run += v.y;
        int a2 = run; run += v.z;
        int a3 = run; run += v.w;
        ((int4*)(pbc + j * CB))[c] = make_int4(a0, a1, a2, a3);
    }
}

// packed edge record: (src << 8) | (dst & 255). bin implied by position.
__global__ __launch_bounds__(256) void scat_k(const int* __restrict__ src,
                                              const int* __restrict__ dst,
                                              const int* __restrict__ pbc,
                                              uint32* __restrict__ ebuf, int E) {
    __shared__ int cur[NBIN];
    cur[threadIdx.x] = pbc[threadIdx.x * CB + blockIdx.x];
    __syncthreads();
    const int chunk = (E + CB - 1) / CB;
    const int lo = blockIdx.x * chunk, hi = min(E, lo + chunk);
    for (int i = lo + threadIdx.x; i < hi; i += 256) {
        int d = dst[i];
        int p = atomicAdd(&cur[d >> 8], 1);      // LDS atomic
        ebuf[p] = ((uint32)src[i] << 8) | (uint32)(d & 255);
    }
}

// one block per bin (256 nodes): CSR rows + elist (src ids, L2-local window) +
// xs[v] = x[v]*dinv[v] as bf16 (pre-scaled messages) + dinv.
__global__ __launch_bounds__(256) void fill2_k(
    const uint32* __restrict__ ebuf, const int* __restrict__ bb,
    int* __restrict__ row_start, int* __restrict__ elist,
    const void* __restrict__ xv, const int* __restrict__ flag,
    uint2* __restrict__ xs, float* __restrict__ dinv, int n) {
    __shared__ int cntl[NBIN], curl[NBIN], sd[NBIN];
    const int j = blockIdx.x, t = threadIdx.x;
    const int lo = j << 8;
    const int hi = min(n, lo + 256);
    const int nn = hi - lo;
    if (nn <= 0) return;
    const int eb = bb[j], ee = bb[j + 1];

    cntl[t] = 0;
    __syncthreads();
    for (int i = eb + t; i < ee; i += 256)
        atomicAdd(&cntl[ebuf[i] & 255u], 1);     // LDS atomic
    __syncthreads();
    int cv = cntl[t];
    sd[t] = cv;
    __syncthreads();
    for (int off = 1; off < NBIN; off <<= 1) {
        int x = (t >= off) ? sd[t - off] : 0;
        __syncthreads();
        sd[t] += x;
        __syncthreads();
    }
    int pref = sd[t] - cv;                        // exclusive
    if (t < nn) row_start[lo + t] = eb + pref;
    curl[t] = pref;
    __syncthreads();
    for (int i = eb + t; i < ee; i += 256) {
        uint32 e = ebuf[i];
        int p = atomicAdd(&curl[e & 255u], 1);    // LDS atomic
        elist[eb + p] = (int)(e >> 8);
    }
    // per-thread node row: xs = x * dinv, bf16
    const int v = lo + t;
    if (v < hi) {
        const bool bf = (*flag != 0);
        float d = rsqrtf((float)(cntl[t] + 1));
        dinv[v] = d;
        if (bf) {
#pragma unroll
            for (int c = 0; c < 16; ++c) {
                uint2 u = ((const uint2*)xv)[(size_t)v * 16 + c];
                float f0 = bf_lo(u.x) * d, f1 = bf_hi(u.x) * d;
                float f2 = bf_lo(u.y) * d, f3 = bf_hi(u.y) * d;
                xs[(size_t)v * 16 + c] = make_uint2(pack_bf(f0, f1), pack_bf(f2, f3));
            }
        } else {
#pragma unroll
            for (int c = 0; c < 16; ++c) {
                float4 f = ((const float4*)xv)[(size_t)v * 16 + c];
                xs[(size_t)v * 16 + c] =
                    make_uint2(pack_bf(f.x * d, f.y * d), pack_bf(f.z * d, f.w * d));
            }
        }
    }
}

// ---------------- aggregation: bf16 pre-scaled rows, one wave/node ---------
// B: [n][16] uint2 rows (64ch bf16, already *dinv[src]). Lane j=L&15 covers
// 4 ch (8B), r=L>>4 edge slot -> 4 edges per gather instr, 16-edge batches
// with early break, 4 gathers in flight (R17 structure). NO per-edge scale:
// only the src id is shfl'd; OOB slots masked by m=0. Fold xor(16|32).
// out = dinv[v]*acc + bias.

template <bool BIAS, bool OUT_NATIVE>
__global__ __launch_bounds__(256) void agg_k(
    const uint2* __restrict__ B, const float* __restrict__ dinv,
    const int* __restrict__ row_start, const int* __restrict__ elist,
    const float* __restrict__ bias, void* __restrict__ outv,
    const int* __restrict__ flag, int n) {
    const int v = blockIdx.x * 4 + (threadIdx.x >> 6);
    if (v >= n) return;
    const int L = threadIdx.x & 63;
    const int r = L >> 4;      // edge slot 0..3
    const int j = L & 15;      // uint2 (4ch) within 128B row

    const int rs = row_start[v], re = row_start[v + 1];
    const float dv = dinv[v];

    uint2 su = B[(size_t)v * 16 + j];
    float a0 = 0.f, a1 = 0.f, a2 = 0.f, a3 = 0.f;
    if (r == 0) {              // self-loop (row already has dinv folded)
        a0 = bf_lo(su.x); a1 = bf_hi(su.x);
        a2 = bf_lo(su.y); a3 = bf_hi(su.y);
    }

    for (int base = rs; base < re; base += 64) {
        int ed = elist[min(base + L, re - 1)];   // 64 edges, one per lane
#pragma unroll 1
        for (int k = 0; k < 4; ++k) {            // wave-uniform 16-edge batches
            if (base + k * 16 >= re) break;
#pragma unroll
            for (int t = 0; t < 4; ++t) {        // 4 gathers in flight
                int e = k * 16 + t * 4 + r;
                int s = __shfl(ed, e);
                float m = (base + e < re) ? 1.f : 0.f;
                uint2 u = B[(size_t)s * 16 + j];
                a0 = fmaf(m, bf_lo(u.x), a0);
                a1 = fmaf(m, bf_hi(u.x), a1);
                a2 = fmaf(m, bf_lo(u.y), a2);
                a3 = fmaf(m, bf_hi(u.y), a3);
            }
        }
    }

    a0 += __shfl_xor(a0, 16); a1 += __shfl_xor(a1, 16);
    a2 += __shfl_xor(a2, 16); a3 += __shfl_xor(a3, 16);
    a0 += __shfl_xor(a0, 32); a1 += __shfl_xor(a1, 32);
    a2 += __shfl_xor(a2, 32); a3 += __shfl_xor(a3, 32);

    if (L < 16) {
        float b0 = 0.f, b1 = 0.f, b2 = 0.f, b3 = 0.f;
        if constexpr (BIAS) {
            float4 bv = ((const float4*)bias)[j];
            b0 = bv.x; b1 = bv.y; b2 = bv.z; b3 = bv.w;
        }
        float v0 = fmaf(dv, a0, b0), v1 = fmaf(dv, a1, b1);
        float v2 = fmaf(dv, a2, b2), v3 = fmaf(dv, a3, b3);
        if constexpr (OUT_NATIVE) {
            if (*flag != 0) {
                ((uint2*)outv)[(size_t)v * 16 + j] =
                    make_uint2(pack_bf(v0, v1), pack_bf(v2, v3));
            } else {
                ((float4*)outv)[(size_t)v * 16 + j] = make_float4(v0, v1, v2, v3);
            }
        } else {
            ((uint2*)outv)[(size_t)v * 16 + j] =
                make_uint2(pack_bf(v0, v1), pack_bf(v2, v3));
        }
    }
}

// ---------------- BN stats over bf16 [n,C] buffer ----------------
// uint2 per lane (4 channels); 256 blocks (small atomic fan-in).

template <int C2>
__global__ __launch_bounds__(256) void stat_k(const uint2* __restrict__ buf,
                                              float* __restrict__ stats, int n) {
    constexpr int LPR = C2 / 2;      // lanes per row
    constexpr int RPB = 256 / LPR;   // rows per block-iteration
    constexpr int C = 2 * C2;
    const int lp = threadIdx.x % LPR;
    const int rg = threadIdx.x / LPR;
    float s0 = 0.f, s1 = 0.f, s2 = 0.f, s3 = 0.f;
    float q0 = 0.f, q1 = 0.f, q2 = 0.f, q3 = 0.f;
    for (int r = blockIdx.x * RPB + rg; r < n; r += gridDim.x * RPB) {
        uint2 u = buf[(size_t)r * LPR + lp];
        float f0 = bf_lo(u.x), f1 = bf_hi(u.x);
        float f2 = bf_lo(u.y), f3 = bf_hi(u.y);
        s0 += f0; q0 = fmaf(f0, f0, q0);
        s1 += f1; q1 = fmaf(f1, f1, q1);
        s2 += f2; q2 = fmaf(f2, f2, q2);
        s3 += f3; q3 = fmaf(f3, f3, q3);
    }
    __shared__ float sd[2 * C];
    for (int i = threadIdx.x; i < 2 * C; i += 256) sd[i] = 0.f;
    __syncthreads();
    atomicAdd(&sd[4 * lp + 0], s0);
    atomicAdd(&sd[4 * lp + 1], s1);
    atomicAdd(&sd[4 * lp + 2], s2);
    atomicAdd(&sd[4 * lp + 3], s3);
    atomicAdd(&sd[C + 4 * lp + 0], q0);
    atomicAdd(&sd[C + 4 * lp + 1], q1);
    atomicAdd(&sd[C + 4 * lp + 2], q2);
    atomicAdd(&sd[C + 4 * lp + 3], q3);
    __syncthreads();
    for (int i = threadIdx.x; i < 2 * C; i += 256) atomicAdd(&stats[i], sd[i]);
}

// ---------------- GEMM: out = epilogue( act(A) @ W ) ----------------
// A [n,K] bf16 flat, W [K,N] f32. XOR-swizzled Ast staging.
// AFFS: in-block BN coefs from raw stats. BIAS: +bias[col]. DINV: row scale
// (pre-folds dinv into the bf16 output rows for the next aggregation).

template <int K, int N, int MR, bool AFFS, bool BIAS, bool DINV>
__global__ __launch_bounds__(256) void gemm_k(
    const __hip_bfloat16* __restrict__ A, const float* __restrict__ W,
    const float* __restrict__ stats, const float* __restrict__ g,
    const float* __restrict__ be, float invN,
    const float* __restrict__ bias, const float* __restrict__ dinv,
    __hip_bfloat16* __restrict__ out, int n) {
    constexpr int CG = N / 4;        // threads across columns
    constexpr int RG = 256 / CG;     // row groups
    constexpr int TM = RG * MR;      // rows per block
    __shared__ __align__(16) float Ws[K * N];
    __shared__ __align__(16) float Ast[K * TM];
    __shared__ float cf[AFFS ? 2 * K : 1];

    const int tid = threadIdx.x;
    if constexpr (AFFS) {
        if (tid < K) {
            float mean = stats[tid] * invN;
            float var  = fmaxf(fmaf(-mean, mean, stats[K + tid] * invN), 0.f);
            float a    = g[tid] * rsqrtf(var + EPS_BN);
            cf[tid]     = a;
            cf[K + tid] = be[tid] - mean * a;
        }
        __syncthreads();
    }

    for (int i = tid; i < K * N / 4; i += 256)
        ((float4*)Ws)[i] = ((const float4*)W)[i];

    const int row0 = blockIdx.x * TM;
    constexpr int KC = K / 4;
    for (int i = tid; i < TM * KC; i += 256) {
        int r  = i / KC;
        int c4 = (i - r * KC) * 4;
        int gr = row0 + r;
        float f0 = 0.f, f1 = 0.f, f2 = 0.f, f3 = 0.f;
        if (gr < n) {
            uint2 u = *(const uint2*)(A + (size_t)gr * K + c4);
            f0 = bf_lo(u.x); f1 = bf_hi(u.x);
            f2 = bf_lo(u.y); f3 = bf_hi(u.y);
            if constexpr (AFFS) {
                f0 = fmaf(cf[c4 + 0], f0, cf[K + c4 + 0]); f0 = f0 > 0.f ? f0 : LEAKY * f0;
                f1 = fmaf(cf[c4 + 1], f1, cf[K + c4 + 1]); f1 = f1 > 0.f ? f1 : LEAKY * f1;
                f2 = fmaf(cf[c4 + 2], f2, cf[K + c4 + 2]); f2 = f2 > 0.f ? f2 : LEAKY * f2;
                f3 = fmaf(cf[c4 + 3], f3, cf[K + c4 + 3]); f3 = f3 > 0.f ? f3 : LEAKY * f3;
            }
        }
        const int rr = r ^ (4 * ((c4 >> 2) & 7));
        Ast[(c4 + 0) * TM + rr] = f0;
        Ast[(c4 + 1) * TM + rr] = f1;
        Ast[(c4 + 2) * TM + rr] = f2;
        Ast[(c4 + 3) * TM + rr] = f3;
    }
    __syncthreads();

    const int tr = tid / CG, tc = tid % CG;
    float acc[MR][4];
#pragma unroll
    for (int m = 0; m < MR; ++m)
#pragma unroll
        for (int j = 0; j < 4; ++j) acc[m][j] = 0.f;

#pragma unroll 4
    for (int k = 0; k < K; ++k) {
        float4 w = *(const float4*)&Ws[k * N + tc * 4];
        const int sk = 4 * ((k >> 2) & 7);
        float am[MR];
        if constexpr (MR == 4) {
            float4 t = *(const float4*)&Ast[k * TM + ((tr * 4) ^ sk)];
            am[0] = t.x; am[1] = t.y; am[2] = t.z; am[3] = t.w;
        } else {
            float2 t = *(const float2*)&Ast[k * TM + ((tr * 2) ^ sk)];
            am[0] = t.x; am[1] = t.y;
        }
#pragma unroll
        for (int m = 0; m < MR; ++m) {
            acc[m][0] = fmaf(am[m], w.x, acc[m][0]);
            acc[m][1] = fmaf(am[m], w.y, acc[m][1]);
            acc[m][2] = fmaf(am[m], w.z, acc[m][2]);
            acc[m][3] = fmaf(am[m], w.w, acc[m][3]);
        }
    }

    float bv[4] = {0.f, 0.f, 0.f, 0.f};
    if constexpr (BIAS) {
#pragma unroll
        for (int j = 0; j < 4; ++j) bv[j] = bias[tc * 4 + j];
    }

#pragma unroll
    for (int m = 0; m < MR; ++m) {
        int gr = row0 + tr * MR + m;
        float sc = 1.f;
        if constexpr (DINV) sc = (gr < n) ? dinv[gr] : 0.f;
        float val[4];
#pragma unroll
        for (int j = 0; j < 4; ++j) {
            float v = acc[m][j];
            if constexpr (BIAS) v += bv[j];
            else                v *= sc;
            val[j] = v;
        }
        if (gr < n) {
            __attribute__((aligned(8))) __hip_bfloat16 pk[4];
#pragma unroll
            for (int j = 0; j < 4; ++j) pk[j] = __float2bfloat16(val[j]);
            *(uint2*)(out + (size_t)gr * N + tc * 4) = *(const uint2*)pk;
        }
    }
}

// ---------------- host ----------------

extern "C" void kernel_launch(void* const* d_in, const int* in_sizes, int n_in,
                              void* d_out, int out_size, void* d_ws, size_t ws_size,
                              hipStream_t stream) {
    const int n = in_sizes[0] / 64;   // 50000
    const int E = in_sizes[1] / 2;    // 800000

    const void* x  = d_in[0];
    const int*  ei = (const int*)d_in[1];

    // workspace carve (256B aligned)
    char* w = (char*)d_ws;
    auto alloc = [&](size_t bytes) -> void* {
        void* p = (void*)w;
        w += (bytes + 255) & ~(size_t)255;
        return p;
    };
    int*   flag      = (int*)alloc(256);
    float* Wf        = (float*)alloc(21120 * 4);            // converted params
    int*   pbc       = (int*)alloc((size_t)CB * NBIN * 4);
    int*   bb        = (int*)alloc((NBIN + 2) * 4);
    int*   row_start = (int*)alloc((size_t)(n + 1) * 4);
    int*   elist     = (int*)alloc((size_t)E * 4);
    uint32* ebuf     = (uint32*)alloc((size_t)E * 4);       // packed (src<<8)|dl
    float* dinv      = (float*)alloc((size_t)n * 4);
    float* stats1    = (float*)alloc(256 * 4);
    float* stats2    = (float*)alloc(128 * 4);
    uint2* xs        = (uint2*)alloc((size_t)n * 16 * 8);   // x*dinv bf16 rows
    __hip_bfloat16* B1 = (__hip_bfloat16*)alloc((size_t)n * 64 * 2);   // AX / hd
    __hip_bfloat16* B2 = (__hip_bfloat16*)alloc((size_t)n * 128 * 2);  // out1/out2

    // param offsets inside Wf
    float* W1f = Wf + 0;     float* b1f = Wf + 8192;
    float* g1f = Wf + 8320;  float* be1f = Wf + 8448;
    float* W2f = Wf + 8576;  float* b2f = Wf + 16768;
    float* g2f = Wf + 16832; float* be2f = Wf + 16896;
    float* W3f = Wf + 16960; float* b3f = Wf + 21056;

    const float invN = 1.0f / (float)n;
    const int nbins = (n + 255) >> 8;        // bins of 256 nodes
    const int ab    = (n + 3) / 4;           // one wave per node, 4 waves/block

    // 1: detect + cvt params + zero stats + bin count (merged, independent)
    setup_cnt_k<<<212, 256, 0, stream>>>((const uint32*)x, flag,
        d_in[2], d_in[3], d_in[4], d_in[5], d_in[6], d_in[7], d_in[8], d_in[9],
        d_in[10], d_in[11], Wf, stats1, stats2, ei + E, pbc, E);
    // 2-4: atomic-free radix CSR build + pre-scaled bf16 xs
    scan2_k<<<1, 256, 0, stream>>>(pbc, bb, row_start + n, E);
    scat_k<<<CB, 256, 0, stream>>>(ei, ei + E, pbc, ebuf, E);
    fill2_k<<<nbins, 256, 0, stream>>>(ebuf, bb, row_start, elist, x, flag,
                                       xs, dinv, n);

    // Layer 1 (aggregate-first): B1 = A_hat x ; out1(B2) = B1@W1 + b1 ; stats1
    agg_k<false, false><<<ab, 256, 0, stream>>>(xs, dinv, row_start, elist,
                                                nullptr, B1, flag, n);
    gemm_k<64, 128, 4, false, true, false><<<(n + 31) / 32, 256, 0, stream>>>(
        B1, W1f, nullptr, nullptr, nullptr, 0.f, b1f, nullptr, B2, n);
    stat_k<64><<<256, 256, 0, stream>>>((const uint2*)B2, stats1, n);

    // Layer 2: hd(B1) = (BN+leaky(out1)@W2)*dinv ; out2(B2) = gather + b2 ; stats2
    gemm_k<128, 64, 4, true, false, true><<<(n + 63) / 64, 256, 0, stream>>>(
        B2, W2f, stats1, g1f, be1f, invN, nullptr, dinv, B1, n);
    agg_k<true, false><<<ab, 256, 0, stream>>>((const uint2*)B1, dinv, row_start,
                                               elist, b2f, B2, flag, n);
    stat_k<32><<<256, 256, 0, stream>>>((const uint2*)B2, stats2, n);

    // Layer 3: hd(B1) = (BN+leaky(out2)@W3)*dinv ; out = gather + b3 (native)
    gemm_k<64, 64, 4, true, false, true><<<(n + 63) / 64, 256, 0, stream>>>(
        B2, W3f, stats2, g2f, be2f, invN, nullptr, dinv, B1, n);
    agg_k<true, true><<<ab, 256, 0, stream>>>((const uint2*)B1, dinv, row_start,
                                              elist, b3f, d_out, flag, n);
}